// Round 4
// baseline (1178.362 us; speedup 1.0000x reference)
//
#include <hip/hip_runtime.h>
#include <hip/hip_bf16.h>

#define NTOK 4096   // B*S tokens
#define HD   1024   // hidden
#define ID   4096   // intermediate
#define NE   8      // experts

typedef float  floatx4 __attribute__((ext_vector_type(4)));
typedef __bf16 bf16x8  __attribute__((ext_vector_type(8)));
typedef unsigned short u16;

__device__ __forceinline__ u16 f2bf(float f) {
    union { float f; unsigned int i; } c; c.f = f;
    return (u16)((c.i + 0x7fffu + ((c.i >> 16) & 1u)) >> 16);   // RNE
}

// async global->LDS, 16B per lane; lds must be the wave-uniform chunk base
__device__ __forceinline__ void async_copy16(u16* lds, const u16* g) {
    __builtin_amdgcn_global_load_lds(
        (const __attribute__((address_space(1))) void*)g,
        (__attribute__((address_space(3))) void*)lds, 16, 0, 0);
}

// tanh-approx GELU (validated R3: absmax 0.0078 == erff version)
__device__ __forceinline__ float gelu_fast(float v) {
    const float u = v * (0.7978845608f + 0.0356774081f * v * v);
    const float t = 1.f - 2.f / (__expf(2.f * u) + 1.f);
    return 0.5f * v * (1.f + t);
}

// ---------------- fp32 -> bf16 conversion (8 elems/thread) ----------------
__global__ __launch_bounds__(256) void convert_kernel(
    const float* __restrict__ src, u16* __restrict__ dst)
{
    const size_t i = ((size_t)blockIdx.x * 256 + threadIdx.x) * 8;
    const float4 a = *(const float4*)(src + i);
    const float4 b = *(const float4*)(src + i + 4);
    ushort4 o0, o1;
    o0.x = f2bf(a.x); o0.y = f2bf(a.y); o0.z = f2bf(a.z); o0.w = f2bf(a.w);
    o1.x = f2bf(b.x); o1.y = f2bf(b.y); o1.z = f2bf(b.z); o1.w = f2bf(b.w);
    *(ushort4*)(dst + i)     = o0;
    *(ushort4*)(dst + i + 4) = o1;
}

// ---------------- router: logits -> softmax -> sort desc -> w[rank][n] ----
__global__ __launch_bounds__(256) void router_kernel(
    const float* __restrict__ x, const float* __restrict__ Wr,
    float* __restrict__ wbuf)
{
    const int n    = blockIdx.x * 4 + (threadIdx.x >> 6);
    const int lane = threadIdx.x & 63;
    const float* xr = x + (size_t)n * HD;
    float acc[NE];
#pragma unroll
    for (int e = 0; e < NE; ++e) acc[e] = 0.f;
    for (int h = lane; h < HD; h += 64) {
        const float xv = xr[h];
#pragma unroll
        for (int e = 0; e < NE; ++e) acc[e] += xv * Wr[e * HD + h];
    }
#pragma unroll
    for (int e = 0; e < NE; ++e) {
        float v = acc[e];
#pragma unroll
        for (int off = 32; off > 0; off >>= 1) v += __shfl_xor(v, off, 64);
        acc[e] = v;
    }
    float mx = acc[0];
#pragma unroll
    for (int e = 1; e < NE; ++e) mx = fmaxf(mx, acc[e]);
    float s = 0.f;
#pragma unroll
    for (int e = 0; e < NE; ++e) { acc[e] = __expf(acc[e] - mx); s += acc[e]; }
    const float inv = 1.f / s;
#pragma unroll
    for (int e = 0; e < NE; ++e) acc[e] *= inv;
#pragma unroll
    for (int i = 0; i < NE - 1; ++i)
#pragma unroll
        for (int j = 0; j < NE - 1 - i; ++j) {
            const float a = acc[j], b = acc[j + 1];
            acc[j] = fmaxf(a, b); acc[j + 1] = fminf(a, b);
        }
    if (lane < NE) wbuf[lane * NTOK + n] = acc[lane];
}

// ---------------- shared 128x128 BK=32 bf16 MFMA main loop (m97 structure) -
// A: row-major (rows x ldA), B: row-major (cols x ldB) i.e. B^T input.
__device__ __forceinline__ void gemm_tile(
    const u16* __restrict__ A, const u16* __restrict__ B,
    int ldA, int ldB, int K, int rowBase, int colBase,
    u16* As, u16* Bs, floatx4 acc[4][4])
{
    const int t    = threadIdx.x;
    const int w    = t >> 6;
    const int lane = t & 63;
    const int wm   = w & 1, wn = w >> 1;
    const int quad = lane >> 4, l15 = lane & 15;
    const int srow = lane >> 2;          // 0..15 (staging row within wave chunk)
    const int scol = (lane & 3) << 3;    // 0/8/16/24

    const u16* gA = A + (size_t)(rowBase + w * 16 + srow) * ldA + scol;
    const u16* gB = B + (size_t)(colBase + w * 16 + srow) * ldB + scol;
    u16* ldsA = As + w * 512;            // wave-uniform 1KB chunk base
    u16* ldsB = Bs + w * 512;
    const size_t rstepA = (size_t)64 * ldA;
    const size_t rstepB = (size_t)64 * ldB;

    int aoff[4], boff[4];
#pragma unroll
    for (int i = 0; i < 4; ++i) {
        aoff[i] = (wm * 64 + i * 16 + l15) * 32 + quad * 8;
        boff[i] = (wn * 64 + i * 16 + l15) * 32 + quad * 8;
    }

    for (int k0 = 0; k0 < K; k0 += 32) {
        async_copy16(ldsA,         gA);
        async_copy16(ldsA + 2048,  gA + rstepA);
        async_copy16(ldsB,         gB);
        async_copy16(ldsB + 2048,  gB + rstepB);
        gA += 32; gB += 32;
        __syncthreads();                 // drains vmcnt for global_load_lds
        bf16x8 af[4], bfr[4];
#pragma unroll
        for (int i = 0; i < 4; ++i) {
            af[i]  = *(const bf16x8*)(As + aoff[i]);
            bfr[i] = *(const bf16x8*)(Bs + boff[i]);
        }
#pragma unroll
        for (int mi = 0; mi < 4; ++mi)
#pragma unroll
            for (int ni = 0; ni < 4; ++ni)
                acc[mi][ni] = __builtin_amdgcn_mfma_f32_16x16x32_bf16(
                    af[mi], bfr[ni], acc[mi][ni], 0, 0, 0);
        __syncthreads();                 // LDS reuse guard
    }
}

// ------- GEMM1 (all experts): hmid_e[n][i] = w[e][n]*gelu(X @ W1_e^T) -----
// hmid stored expert-contiguous: hmid + e*NTOK*ID, ld = ID (m97-identical
// addressing for gemm2's A staging). Epilogue transposes through LDS so the
// global writes are 16B/lane, 256B-per-row coalesced.
#define TSTRIDE 136   // halves; 272 B row stride: 16B-aligned, banks spread
__global__ __launch_bounds__(256) void gemm1_kernel(
    const u16* __restrict__ X, const u16* __restrict__ W1b,
    const float* __restrict__ wbuf, u16* __restrict__ hmid)
{
    __shared__ __align__(16) u16 smem[128 * TSTRIDE];   // 34 KB; staging carved below
    u16* As = smem;              // 128*32 halves = 8 KB
    u16* Bs = smem + 4096;       // 8 KB
    floatx4 acc[4][4] = {};
    const int rowBase = blockIdx.y * 128, colBase = blockIdx.x * 128;
    const int e = blockIdx.x >> 5;                    // 32 col-tiles per expert
    const int colLocal = colBase & (ID - 1);
    gemm_tile(X, W1b, HD, HD, HD, rowBase, colBase, As, Bs, acc);

    const int t = threadIdx.x, w = t >> 6, lane = t & 63;
    const int wm = w & 1, wn = w >> 1, quad = lane >> 4, l15 = lane & 15;
    // phase 1: gelu + router weight -> bf16 into LDS tile [row][col]
#pragma unroll
    for (int mi = 0; mi < 4; ++mi)
#pragma unroll
        for (int r = 0; r < 4; ++r) {
            const int row = wm * 64 + mi * 16 + quad * 4 + r;
            const float wv = wbuf[e * NTOK + rowBase + row];
#pragma unroll
            for (int ni = 0; ni < 4; ++ni) {
                const int col = wn * 64 + ni * 16 + l15;
                smem[row * TSTRIDE + col] = f2bf(gelu_fast(acc[mi][ni][r]) * wv);
            }
        }
    __syncthreads();
    // phase 2: coalesced 16B stores; 256 threads cover 16 rows x 128 cols/pass
    u16* hmidE = hmid + (size_t)e * NTOK * ID;
    const int c0 = (t & 15) * 8;
#pragma unroll
    for (int p = 0; p < 8; ++p) {
        const int row = p * 16 + (t >> 4);
        const bf16x8 v = *(const bf16x8*)(smem + row * TSTRIDE + c0);
        *(bf16x8*)(hmidE + (size_t)(rowBase + row) * ID + colLocal + c0) = v;
    }
}

// ------- GEMM2 (one expert per z): slice[z] = hmid_z @ W2_z^T -------------
// grid (NTOK/128, HD/128, NE) = 2048 blocks; blockIdx.x fastest over tokens so
// the 8 col-blocks sharing one hmid row-stripe land on the same XCD (ids
// differ by 32, 32%8==0) -> L2 reuse of the A stripe.
__global__ __launch_bounds__(256) void gemm2_kernel(
    const u16* __restrict__ hmid, const u16* __restrict__ W2b,
    float* __restrict__ accbuf)
{
    __shared__ __align__(16) u16 As[128 * 32];
    __shared__ __align__(16) u16 Bs[128 * 32];
    floatx4 acc[4][4] = {};
    const int rowBase = blockIdx.x * 128;   // tokens
    const int colBase = blockIdx.y * 128;   // hidden
    const int e = blockIdx.z;
    gemm_tile(hmid + (size_t)e * NTOK * ID, W2b + (size_t)e * HD * ID,
              ID, ID, ID, rowBase, colBase, As, Bs, acc);

    float* accs = accbuf + (size_t)e * NTOK * HD;
    const int t = threadIdx.x, w = t >> 6, lane = t & 63;
    const int wm = w & 1, wn = w >> 1, quad = lane >> 4, l15 = lane & 15;
#pragma unroll
    for (int mi = 0; mi < 4; ++mi)
#pragma unroll
        for (int r = 0; r < 4; ++r) {
            const int row = rowBase + wm * 64 + mi * 16 + quad * 4 + r;
#pragma unroll
            for (int ni = 0; ni < 4; ++ni) {
                const int col = colBase + wn * 64 + ni * 16 + l15;
                accs[(size_t)row * HD + col] = acc[mi][ni][r];
            }
        }
}

// ---------------- finalize: out = sum of 8 slices (fp32) ------------------
__global__ __launch_bounds__(256) void finalize_kernel(
    const float* __restrict__ accbuf, float* __restrict__ out)
{
    const size_t NH = (size_t)NTOK * HD;
    const size_t i = ((size_t)blockIdx.x * 256 + threadIdx.x) * 4;
    float4 o = *(const float4*)(accbuf + i);
#pragma unroll
    for (int z = 1; z < NE; ++z) {
        const float4 a = *(const float4*)(accbuf + z * NH + i);
        o.x += a.x; o.y += a.y; o.z += a.z; o.w += a.w;
    }
    *(float4*)(out + i) = o;
}

extern "C" void kernel_launch(void* const* d_in, const int* in_sizes, int n_in,
                              void* d_out, int out_size, void* d_ws, size_t ws_size,
                              hipStream_t stream) {
    const float* x  = (const float*)d_in[0];   // (N, H) fp32
    const float* Wr = (const float*)d_in[1];   // (E, H) fp32
    const float* W1 = (const float*)d_in[2];   // (E, I, H) fp32
    const float* W2 = (const float*)d_in[3];   // (E, H, I) fp32
    float* out = (float*)d_out;                // (N, H) fp32

    // ws layout (bytes), total 456.125 MB of the 512 MiB observed:
    //   wbuf   @ 0           : E*N f32    = 128 KB
    //   Xb     @ 128K        : N*H bf16   = 8 MB
    //   W2b    @ 128K+8M     : E*H*I bf16 = 64 MB
    //   hmid   @ 128K+72M    : E*N*I bf16 = 256 MB   (expert-contiguous)
    //   W1b    @ 128K+328M   : E*I*H bf16 = 64 MB    (dead after gemm1)
    //   accbuf @ 128K+328M   : 8*N*H f32  = 128 MB   (OVERLAPS W1b — safe:
    //                          gemm2 writes it only after gemm1 is done)
    const size_t MB = 1024 * 1024;
    char* ws = (char*)d_ws;
    float* wbuf   = (float*)ws;
    u16*   Xb     = (u16*)(ws + 131072);
    u16*   W2b    = (u16*)(ws + 131072 + 8 * MB);
    u16*   hmid   = (u16*)(ws + 131072 + 72 * MB);
    u16*   W1b    = (u16*)(ws + 131072 + 328 * MB);
    float* accbuf = (float*)(ws + 131072 + 328 * MB);
    if (ws_size < 131072 + 456 * MB) return;   // fail loudly rather than corrupt

    convert_kernel<<<dim3((NTOK * HD) / 2048), 256, 0, stream>>>(x, Xb);
    convert_kernel<<<dim3((NE * ID * HD) / 2048), 256, 0, stream>>>(W1, W1b);
    convert_kernel<<<dim3((NE * HD * ID) / 2048), 256, 0, stream>>>(W2, W2b);
    router_kernel<<<dim3(NTOK / 4), 256, 0, stream>>>(x, Wr, wbuf);

    gemm1_kernel<<<dim3(NE * ID / 128, NTOK / 128), 256, 0, stream>>>(
        Xb, W1b, wbuf, hmid);
    gemm2_kernel<<<dim3(NTOK / 128, HD / 128, NE), 256, 0, stream>>>(
        hmid, W2b, accbuf);
    finalize_kernel<<<dim3(NTOK * HD / 1024), 256, 0, stream>>>(accbuf, out);
}